// Round 10
// baseline (616.592 us; speedup 1.0000x reference)
//
#include <hip/hip_runtime.h>
#include <hip/hip_cooperative_groups.h>
#include <float.h>

// CURAttention MI355X — Round 10: cooperative NS mega-kernel.
// mergeprep + 11 NS GEMM dispatches -> ONE hipLaunchCooperativeKernel with 11
// grid.sync()s (256 blocks = 1/CU). Stage math byte-identical to R9.
// 18 -> 7 dispatches total.

#define G    16
#define NSEQ 4096
#define DH   64
#define MSEL 256
#define NSL  16

namespace cg = cooperative_groups;

typedef __attribute__((ext_vector_type(8))) short short8;
typedef __attribute__((ext_vector_type(4))) float floatx4;
typedef __attribute__((ext_vector_type(4))) unsigned short ushort4v;
typedef unsigned short ush;

static __device__ __forceinline__ ush f2b(float x) {
    union { float f; unsigned u; } c{x};
    unsigned r = c.u + 0x7FFFu + ((c.u >> 16) & 1u);   // RNE
    return (ush)(r >> 16);
}
static __device__ __forceinline__ float b2f(ush h) {
    union { unsigned u; float f; } c{(unsigned)h << 16};
    return c.f;
}
static __device__ __forceinline__ void split_store(ush* __restrict__ h, ush* __restrict__ l,
                                                   int off, float4 v, float scale) {
    float a0 = v.x * scale, a1 = v.y * scale, a2 = v.z * scale, a3 = v.w * scale;
    ush h0 = f2b(a0), h1 = f2b(a1), h2 = f2b(a2), h3 = f2b(a3);
    ushort4v hv = { h0, h1, h2, h3 };
    ushort4v lv = { f2b(a0 - b2f(h0)), f2b(a1 - b2f(h1)), f2b(a2 - b2f(h2)), f2b(a3 - b2f(h3)) };
    *(ushort4v*)&h[off] = hv;
    *(ushort4v*)&l[off] = lv;
}
static __device__ __forceinline__ floatx4 mfma3(short8 ah, short8 al, short8 bh, short8 bl, floatx4 acc) {
    acc = __builtin_amdgcn_mfma_f32_16x16x32_bf16(al, bh, acc, 0, 0, 0);
    acc = __builtin_amdgcn_mfma_f32_16x16x32_bf16(ah, bl, acc, 0, 0, 0);
    acc = __builtin_amdgcn_mfma_f32_16x16x32_bf16(ah, bh, acc, 0, 0, 0);
    return acc;
}

// ---------------- row sums + K row-norm^2 ----------------
__global__ __launch_bounds__(256) void rowsum_kernel(const float* __restrict__ Q, const float* __restrict__ K,
                                                     float* __restrict__ sumQ, float* __restrict__ sumK,
                                                     float* __restrict__ k2) {
    long row = (long)blockIdx.x * 16 + (threadIdx.x >> 4);
    int c4 = (threadIdx.x & 15) * 4;
    float4 q = *(const float4*)(Q + row * DH + c4);
    float4 k = *(const float4*)(K + row * DH + c4);
    float qs = q.x + q.y + q.z + q.w;
    float ks = k.x + k.y + k.z + k.w;
    float k2s = k.x * k.x + k.y * k.y + k.z * k.z + k.w * k.w;
#pragma unroll
    for (int off = 8; off; off >>= 1) {
        qs += __shfl_xor(qs, off); ks += __shfl_xor(ks, off); k2s += __shfl_xor(k2s, off);
    }
    if ((threadIdx.x & 15) == 0) { sumQ[row] = qs; sumK[row] = ks; k2[row] = k2s; }
}

// ---------------- top-256 + per-g max K-norm^2 + colsum zero ----------------
__global__ __launch_bounds__(256) void topk_select(const float* __restrict__ sumQ, const float* __restrict__ sumK,
                                                   int* __restrict__ idxQ, int* __restrict__ idxK,
                                                   const float* __restrict__ k2, float* __restrict__ Kmax2,
                                                   float* __restrict__ colsum) {
    __shared__ unsigned red[4];
    __shared__ float redf[4];
    __shared__ unsigned eqpre[64];
    __shared__ unsigned cnt_sel;
    int g = blockIdx.x, which = blockIdx.y;
    const float* s = (which ? sumK : sumQ) + (long)g * NSEQ;
    int* out = (which ? idxK : idxQ) + g * MSEL;
    int t = threadIdx.x, lane = t & 63, wid = t >> 6;
    if (which == 0) colsum[g * 256 + t] = 0.f;
    unsigned k[16];
#pragma unroll
    for (int i = 0; i < 16; i++) {
        unsigned u = __float_as_uint(s[t + 256 * i]);
        k[i] = (u & 0x80000000u) ? ~u : (u | 0x80000000u);
    }
    unsigned T = 0;
    for (int b = 31; b >= 0; b--) {
        unsigned trial = T | (1u << b);
        int c = 0;
#pragma unroll
        for (int i = 0; i < 16; i++) c += (k[i] >= trial);
#pragma unroll
        for (int off = 32; off; off >>= 1) c += __shfl_xor(c, off);
        __syncthreads();
        if (lane == 0) red[wid] = (unsigned)c;
        __syncthreads();
        unsigned tot = red[0] + red[1] + red[2] + red[3];
        if (tot == MSEL) { T = trial; break; }
        if (tot > MSEL) T = trial;
    }
    int cg2 = 0;
#pragma unroll
    for (int i = 0; i < 16; i++) cg2 += (k[i] > T);
#pragma unroll
    for (int off = 32; off; off >>= 1) cg2 += __shfl_xor(cg2, off);
    __syncthreads();
    if (lane == 0) red[wid] = (unsigned)cg2;
    if (t == 0) cnt_sel = 0;
    __syncthreads();
    unsigned ngreater = red[0] + red[1] + red[2] + red[3];
    unsigned want_eq = MSEL - ngreater;
#pragma unroll
    for (int i = 0; i < 16; i++) {
        unsigned long long be = __ballot(k[i] == T);
        if (lane == 0) eqpre[i * 4 + wid] = (unsigned)__popcll(be);
    }
    __syncthreads();
    if (t == 0) {
        unsigned run = 0;
        for (int j = 0; j < 64; j++) { unsigned c = eqpre[j]; eqpre[j] = run; run += c; }
    }
    __syncthreads();
#pragma unroll
    for (int i = 0; i < 16; i++) {
        int idx = t + 256 * i;
        unsigned long long lt = (1ull << lane) - 1;
        bool gt = (k[i] > T);
        unsigned long long bg = __ballot(gt);
        unsigned wbase = 0;
        if (lane == 0) wbase = atomicAdd(&cnt_sel, (unsigned)__popcll(bg));
        wbase = __shfl((int)wbase, 0);
        if (gt) out[wbase + __popcll(bg & lt)] = idx;
        bool eq = (k[i] == T);
        unsigned long long be = __ballot(eq);
        if (eq) {
            unsigned rank = eqpre[i * 4 + wid] + (unsigned)__popcll(be & lt);
            if (rank < want_eq) out[ngreater + rank] = idx;
        }
    }
    if (which == 1) {
        float mx = 0.f;
#pragma unroll
        for (int i = 0; i < 16; i++) mx = fmaxf(mx, k2[(long)g * NSEQ + t + 256 * i]);
#pragma unroll
        for (int off = 32; off; off >>= 1) mx = fmaxf(mx, __shfl_xor(mx, off));
        __syncthreads();
        if (lane == 0) redf[wid] = mx;
        __syncthreads();
        if (t == 0) Kmax2[g] = fmaxf(fmaxf(redf[0], redf[1]), fmaxf(redf[2], redf[3]));
    }
}

// ---------------- gather ----------------
__global__ __launch_bounds__(256) void gather_kernel(const float* __restrict__ Q, const float* __restrict__ K,
                                                     const int* __restrict__ idxQ, const int* __restrict__ idxK,
                                                     const float* __restrict__ Kmax2,
                                                     float* __restrict__ nr,
                                                     ush* __restrict__ ncH, ush* __restrict__ ncL,
                                                     float* __restrict__ Mb) {
    int wid = threadIdx.x >> 6, lane = threadIdx.x & 63;
    long t = (long)blockIdx.x * 4 + wid;
    long g = t >> 8;
    int iq = idxQ[t], ik = idxK[t];
    float qv = Q[(g * NSEQ + iq) * DH + lane] * 0.125f;
    nr[t * DH + lane] = qv;
    float kv = K[(g * NSEQ + ik) * DH + lane];
    ush h = f2b(kv);
    ncH[t * DH + lane] = h;
    ncL[t * DH + lane] = f2b(kv - b2f(h));
    float n2 = qv * qv;
#pragma unroll
    for (int off = 32; off; off >>= 1) n2 += __shfl_xor(n2, off);
    if (lane == 0) Mb[t] = sqrtf(n2 * Kmax2[g]);
}

// ---------------- flash r->exp(S-M)->RV partial sums ----------------
__global__ __launch_bounds__(256, 4) void flash_rv(const float* __restrict__ nr, const float* __restrict__ K,
                                                   const float* __restrict__ V, const float* __restrict__ Mb,
                                                   float* __restrict__ Lp, float* __restrict__ RVp) {
    __shared__ __align__(16) ush B1h[64 * 72];
    __shared__ __align__(16) ush B1l[64 * 72];
    __shared__ __align__(16) ush Ph[64 * 72];
    __shared__ float msh[64];
    __shared__ float lred[64][2];
    int ns = blockIdx.x, s = blockIdx.y, g = blockIdx.z;
    int t = threadIdx.x, lane = t & 63, w = t >> 6;
    int wr = w >> 1, wc = w & 1, ml = lane & 15, quad = lane >> 4;
    int lr = t >> 2, lq = t & 3;
    const float* nrg = nr + (long)g * 16384 + (long)s * 64 * 64;
    const float* Kg  = K + (long)g * 262144 + (long)ns * 256 * 64;
    const float* Vg  = V + (long)g * 262144 + (long)ns * 256 * 64;
    short8 Ah[2][2], Al[2][2];
#pragma unroll
    for (int i2 = 0; i2 < 2; i2++)
#pragma unroll
        for (int kq = 0; kq < 2; kq++) {
            const float* p = nrg + (wr * 32 + i2 * 16 + ml) * 64 + kq * 32 + quad * 8;
            float4 f0 = *(const float4*)p;
            float4 f1 = *(const float4*)(p + 4);
            float vals[8] = { f0.x, f0.y, f0.z, f0.w, f1.x, f1.y, f1.z, f1.w };
            short8 hh, ll;
#pragma unroll
            for (int j = 0; j < 8; j++) {
                ush h = f2b(vals[j]);
                hh[j] = (short)h;
                ll[j] = (short)f2b(vals[j] - b2f(h));
            }
            Ah[i2][kq] = hh; Al[i2][kq] = ll;
        }
    if (t < 64) msh[t] = Mb[g * 256 + s * 64 + t];
    float lsum[2][4] = {};
    floatx4 acc[2][2] = {};
    int vn = t >> 2, vdq = (t & 3) * 16;
    for (int it = 0; it < 4; it++) {
        __syncthreads();
        float4 kv[4], vv[4];
#pragma unroll
        for (int q = 0; q < 4; q++) kv[q] = *(const float4*)(Kg + (long)(it * 64 + lr) * 64 + lq * 16 + q * 4);
#pragma unroll
        for (int q = 0; q < 4; q++) vv[q] = *(const float4*)(Vg + (long)(it * 64 + vn) * 64 + vdq + q * 4);
#pragma unroll
        for (int q = 0; q < 4; q++) split_store(B1h, B1l, lr * 72 + lq * 16 + q * 4, kv[q], 1.0f);
        __syncthreads();
        floatx4 sa[2][2] = {};
#pragma unroll
        for (int kq = 0; kq < 2; kq++) {
            short8 b0h = *(const short8*)&B1h[(wc * 32 + ml) * 72 + kq * 32 + quad * 8];
            short8 b0l = *(const short8*)&B1l[(wc * 32 + ml) * 72 + kq * 32 + quad * 8];
            short8 b1h = *(const short8*)&B1h[(wc * 32 + 16 + ml) * 72 + kq * 32 + quad * 8];
            short8 b1l = *(const short8*)&B1l[(wc * 32 + 16 + ml) * 72 + kq * 32 + quad * 8];
            sa[0][0] = mfma3(Ah[0][kq], Al[0][kq], b0h, b0l, sa[0][0]);
            sa[0][1] = mfma3(Ah[0][kq], Al[0][kq], b1h, b1l, sa[0][1]);
            sa[1][0] = mfma3(Ah[1][kq], Al[1][kq], b0h, b0l, sa[1][0]);
            sa[1][1] = mfma3(Ah[1][kq], Al[1][kq], b1h, b1l, sa[1][1]);
        }
        __syncthreads();
#pragma unroll
        for (int i2 = 0; i2 < 2; i2++)
#pragma unroll
            for (int r = 0; r < 4; r++) {
                int row = wr * 32 + i2 * 16 + quad * 4 + r;
                float M = msh[row];
                float p0 = __expf(sa[i2][0][r] - M);
                float p1 = __expf(sa[i2][1][r] - M);
                lsum[i2][r] += p0 + p1;
                Ph[row * 72 + wc * 32 + ml] = f2b(p0);
                Ph[row * 72 + wc * 32 + 16 + ml] = f2b(p1);
            }
#pragma unroll
        for (int q = 0; q < 4; q++)
#pragma unroll
            for (int c = 0; c < 4; c++) {
                int d = vdq + q * 4 + c;
                int addr = d * 72 + ((((vn >> 3) ^ ((d >> 4) & 3)) << 3) | (vn & 7));
                B1h[addr] = f2b((&vv[q].x)[c]);
            }
        __syncthreads();
#pragma unroll
        for (int kq = 0; kq < 2; kq++) {
            short8 a0 = *(const short8*)&Ph[(wr * 32 + ml) * 72 + kq * 32 + quad * 8];
            short8 a1 = *(const short8*)&Ph[(wr * 32 + 16 + ml) * 72 + kq * 32 + quad * 8];
            int nb = kq * 4 + quad;
            short8 b0 = *(const short8*)&B1h[(wc * 32 + ml) * 72 + ((nb ^ (2 * wc)) << 3)];
            short8 b1 = *(const short8*)&B1h[(wc * 32 + 16 + ml) * 72 + ((nb ^ (2 * wc + 1)) << 3)];
            acc[0][0] = __builtin_amdgcn_mfma_f32_16x16x32_bf16(a0, b0, acc[0][0], 0, 0, 0);
            acc[0][1] = __builtin_amdgcn_mfma_f32_16x16x32_bf16(a0, b1, acc[0][1], 0, 0, 0);
            acc[1][0] = __builtin_amdgcn_mfma_f32_16x16x32_bf16(a1, b0, acc[1][0], 0, 0, 0);
            acc[1][1] = __builtin_amdgcn_mfma_f32_16x16x32_bf16(a1, b1, acc[1][1], 0, 0, 0);
        }
    }
#pragma unroll
    for (int i2 = 0; i2 < 2; i2++)
#pragma unroll
        for (int r = 0; r < 4; r++) {
            float v = lsum[i2][r];
#pragma unroll
            for (int off = 8; off; off >>= 1) v += __shfl_xor(v, off);
            if (ml == 0) lred[wr * 32 + i2 * 16 + quad * 4 + r][wc] = v;
        }
    __syncthreads();
    long p = ((long)(g * 4 + s)) * NSL + ns;
    if (t < 64) Lp[p * 64 + t] = lred[t][0] + lred[t][1];
    float* rvp = RVp + p * 4096;
#pragma unroll
    for (int i2 = 0; i2 < 2; i2++)
#pragma unroll
        for (int j2 = 0; j2 < 2; j2++)
#pragma unroll
            for (int r = 0; r < 4; r++)
                rvp[(wr * 32 + i2 * 16 + quad * 4 + r) * 64 + wc * 32 + j2 * 16 + ml] = acc[i2][j2][r];
}

// ---------------- fused c -> softmax -> (X | u + colsum) ----------------
template <int MODE>
__global__ __launch_bounds__(256, 4) void fused_cx(const float* __restrict__ A,
                                                   const ush* __restrict__ ncH, const ush* __restrict__ ncL,
                                                   const ush* __restrict__ WtH, const ush* __restrict__ WtL,
                                                   float* __restrict__ Out, float* __restrict__ colsum,
                                                   float ascale) {
    __shared__ __align__(16) ush SM[18432];
    ush* Ah = SM;            ush* Al = SM + 4608;
    ush* Bh = SM + 9216;     ush* Bl = SM + 13824;
    ush* Ph = SM;            ush* Pl = SM + 4608;
    ush* Wh = SM + 9216;     ush* Wl = SM + 13824;
    __shared__ float pm[256], ps[256], Mr[64], Lr[64];
    int strip = blockIdx.x, g = blockIdx.y;
    int t = threadIdx.x, lane = t & 63, w = t >> 6;
    int wr = w >> 1, wc = w & 1, ml = lane & 15, quad = lane >> 4;
    int lr = t >> 2, lq = t & 3;
    long aRows = (MODE == 0) ? 4096 : 256;
    const float* Ag = A + (long)g * aRows * 64 + (long)strip * 64 * 64;
    const ush* ncHg = ncH + (long)g * 16384;
    const ush* ncLg = ncL + (long)g * 16384;
#pragma unroll
    for (int q = 0; q < 4; q++) {
        float4 v = *(const float4*)(Ag + lr * 64 + lq * 16 + q * 4);
        split_store(Ah, Al, lr * 72 + lq * 16 + q * 4, v, ascale);
    }
    floatx4 sacc[4][4] = {};
    for (int c = 0; c < 4; c++) {
        __syncthreads();
        {
            const ush* sH = ncHg + (c * 64 + lr) * 64;
            const ush* sL = ncLg + (c * 64 + lr) * 64;
            *(uint4*)&Bh[lr * 72 + lq * 8]       = *(const uint4*)&sH[lq * 8];
            *(uint4*)&Bh[lr * 72 + (lq + 4) * 8] = *(const uint4*)&sH[(lq + 4) * 8];
            *(uint4*)&Bl[lr * 72 + lq * 8]       = *(const uint4*)&sL[lq * 8];
            *(uint4*)&Bl[lr * 72 + (lq + 4) * 8] = *(const uint4*)&sL[(lq + 4) * 8];
        }
        __syncthreads();
#pragma unroll
        for (int kq = 0; kq < 2; kq++) {
            short8 bh = *(const short8*)&Bh[(w * 16 + ml) * 72 + kq * 32 + quad * 8];
            short8 bl = *(const short8*)&Bl[(w * 16 + ml) * 72 + kq * 32 + quad * 8];
#pragma unroll
            for (int i = 0; i < 4; i++) {
                short8 afh = *(const short8*)&Ah[(16 * i + ml) * 72 + kq * 32 + quad * 8];
                short8 afl = *(const short8*)&Al[(16 * i + ml) * 72 + kq * 32 + quad * 8];
                sacc[c][i] = mfma3(afh, afl, bh, bl, sacc[c][i]);
            }
        }
    }
#pragma unroll
    for (int i = 0; i < 4; i++)
#pragma unroll
        for (int r = 0; r < 4; r++) {
            float mx = fmaxf(fmaxf(sacc[0][i][r], sacc[1][i][r]), fmaxf(sacc[2][i][r], sacc[3][i][r]));
#pragma unroll
            for (int off = 8; off; off >>= 1) mx = fmaxf(mx, __shfl_xor(mx, off));
            if (ml == 0) pm[(16 * i + quad * 4 + r) * 4 + w] = mx;
        }
    __syncthreads();
    if (t < 64) Mr[t] = fmaxf(fmaxf(pm[t * 4], pm[t * 4 + 1]), fmaxf(pm[t * 4 + 2], pm[t * 4 + 3]));
    __syncthreads();
#pragma unroll
    for (int i = 0; i < 4; i++)
#pragma unroll
        for (int r = 0; r < 4; r++) {
            int row = 16 * i + quad * 4 + r;
            float M = Mr[row];
            float sum = 0.f;
#pragma unroll
            for (int c = 0; c < 4; c++) {
                float p = __expf(sacc[c][i][r] - M);
                sacc[c][i][r] = p;
                sum += p;
            }
#pragma unroll
            for (int off = 8; off; off >>= 1) sum += __shfl_xor(sum, off);
            if (ml == 0) ps[row * 4 + w] = sum;
        }
    __syncthreads();
    if (t < 64) Lr[t] = ps[t * 4] + ps[t * 4 + 1] + ps[t * 4 + 2] + ps[t * 4 + 3];
    __syncthreads();
    if (MODE == 1) {
        float invL[4][4];
#pragma unroll
        for (int i = 0; i < 4; i++)
#pragma unroll
            for (int r = 0; r < 4; r++) invL[i][r] = 1.0f / Lr[16 * i + quad * 4 + r];
        float* ug = Out + (long)g * 65536 + (long)strip * 64 * 256;
#pragma unroll
        for (int i = 0; i < 4; i++)
#pragma unroll
            for (int r = 0; r < 4; r++) {
                int row = 16 * i + quad * 4 + r;
#pragma unroll
                for (int c = 0; c < 4; c++)
                    ug[(long)row * 256 + c * 64 + w * 16 + ml] = sacc[c][i][r] * invL[i][r];
            }
#pragma unroll
        for (int c = 0; c < 4; c++) {
            float v = 0.f;
#pragma unroll
            for (int i = 0; i < 4; i++)
#pragma unroll
                for (int r = 0; r < 4; r++) v += sacc[c][i][r] * invL[i][r];
            v += __shfl_xor(v, 16);
            v += __shfl_xor(v, 32);
            if (quad == 0) atomicAdd(&colsum[g * 256 + c * 64 + w * 16 + ml], v);
        }
        return;
    }
    floatx4 xacc[2][2] = {};
    const ush* wHg = WtH + (long)g * 16384;
    const ush* wLg = WtL + (long)g * 16384;
#pragma unroll
    for (int h = 0; h < 4; h++) {
        __syncthreads();
#pragma unroll
        for (int i = 0; i < 4; i++)
#pragma unroll
            for (int r = 0; r < 4; r++) {
                int row = 16 * i + quad * 4 + r;
                float p = sacc[h][i][r];
                ush hh = f2b(p);
                Ph[row * 72 + w * 16 + ml] = hh;
                Pl[row * 72 + w * 16 + ml] = f2b(p - b2f(hh));
            }
        {
            const ush* sH = wHg + lr * 256 + h * 64;
            const ush* sL = wLg + lr * 256 + h * 64;
            *(uint4*)&Wh[lr * 72 + lq * 8]       = *(const uint4*)&sH[lq * 8];
            *(uint4*)&Wh[lr * 72 + (lq + 4) * 8] = *(const uint4*)&sH[(lq + 4) * 8];
            *(uint4*)&Wl[lr * 72 + lq * 8]       = *(const uint4*)&sL[lq * 8];
            *(uint4*)&Wl[lr * 72 + (lq + 4) * 8] = *(const uint4*)&sL[(lq + 4) * 8];
        }
        __syncthreads();
#pragma unroll
        for (int kq = 0; kq < 2; kq++) {
            short8 a0h = *(const short8*)&Ph[(wr * 32 + ml) * 72 + kq * 32 + quad * 8];
            short8 a0l = *(const short8*)&Pl[(wr * 32 + ml) * 72 + kq * 32 + quad * 8];
            short8 a1h = *(const short8*)&Ph[(wr * 32 + 16 + ml) * 72 + kq * 32 + quad * 8];
            short8 a1l = *(const short8*)&Pl[(wr * 32 + 16 + ml) * 72 + kq * 32 + quad * 8];
            short8 b0h = *(const short8*)&Wh[(wc * 32 + ml) * 72 + kq * 32 + quad * 8];
            short8 b0l = *(const short8*)&Wl[(wc * 32 + ml) * 72 + kq * 32 + quad * 8];
            short8 b1h = *(const short8*)&Wh[(wc * 32 + 16 + ml) * 72 + kq * 32 + quad * 8];
            short8 b1l = *(const short8*)&Wl[(wc * 32 + 16 + ml) * 72 + kq * 32 + quad * 8];
            xacc[0][0] = mfma3(a0h, a0l, b0h, b0l, xacc[0][0]);
            xacc[0][1] = mfma3(a0h, a0l, b1h, b1l, xacc[0][1]);
            xacc[1][0] = mfma3(a1h, a1l, b0h, b0l, xacc[1][0]);
            xacc[1][1] = mfma3(a1h, a1l, b1h, b1l, xacc[1][1]);
        }
    }
    float* outg = Out + (long)g * 262144 + (long)strip * 64 * 64;
#pragma unroll
    for (int i2 = 0; i2 < 2; i2++)
#pragma unroll
        for (int j2 = 0; j2 < 2; j2++)
#pragma unroll
            for (int r = 0; r < 4; r++) {
                int row = wr * 32 + i2 * 16 + quad * 4 + r;
                outg[(long)row * 64 + wc * 32 + j2 * 16 + ml] = xacc[i2][j2][r] / Lr[row];
            }
}

// ================= cooperative NS mega-kernel =================
struct NSArgs {
    const float* Lp; const float* RVp; ush* RVt;
    const float* u; const float* colsum;
    ush* u_bf; float* scale;
    ush* Va; ush* Vb;
    ush* E_a; ush* Et_a; ush* E_b; ush* Et_b;
    ush* S; ush* St; ush* Pt;
    ush* WtH; ush* WtL;
};

#define NSLD 136

// K=256 GEMM core: stages A (64x256) + B tile(s) into LDS, 32 MFMAs.
template <bool DUAL>
static __device__ __forceinline__ void mm_core(const ush* __restrict__ Ag, const ush* __restrict__ B1g,
                                               const ush* __restrict__ B2g,
                                               ush* As, ush* B1s, ush* B2s,
                                               floatx4 (&acc1)[2][2], floatx4 (&acc2)[2][2], int t) {
    int lr = t >> 2, lq = t & 3;
    int w = t >> 6, lane = t & 63;
    int wr = w >> 1, wc = w & 1, ml = lane & 15, quad = lane >> 4;
#pragma unroll
    for (int h = 0; h < 2; h++) {
        __syncthreads();
#pragma unroll
        for (int rr = 0; rr < 4; rr++) {
            int col = (lq + 4 * rr) * 8;
            *(uint4*)&As[lr * NSLD + col]  = *(const uint4*)(Ag + lr * 256 + h * 128 + col);
            *(uint4*)&B1s[lr * NSLD + col] = *(const uint4*)(B1g + lr * 256 + h * 128 + col);
            if (DUAL) *(uint4*)&B2s[lr * NSLD + col] = *(const uint4*)(B2g + lr * 256 + h * 128 + col);
        }
        __syncthreads();
#pragma unroll
        for (int kq = 0; kq < 4; kq++) {
            int ko = kq * 32 + quad * 8;
            short8 a0 = *(const short8*)&As[(wr * 32 + ml) * NSLD + ko];
            short8 a1 = *(const short8*)&As[(wr * 32 + 16 + ml) * NSLD + ko];
            short8 b10 = *(const short8*)&B1s[(wc * 32 + ml) * NSLD + ko];
            short8 b11 = *(const short8*)&B1s[(wc * 32 + 16 + ml) * NSLD + ko];
            acc1[0][0] = __builtin_amdgcn_mfma_f32_16x16x32_bf16(a0, b10, acc1[0][0], 0, 0, 0);
            acc1[0][1] = __builtin_amdgcn_mfma_f32_16x16x32_bf16(a0, b11, acc1[0][1], 0, 0, 0);
            acc1[1][0] = __builtin_amdgcn_mfma_f32_16x16x32_bf16(a1, b10, acc1[1][0], 0, 0, 0);
            acc1[1][1] = __builtin_amdgcn_mfma_f32_16x16x32_bf16(a1, b11, acc1[1][1], 0, 0, 0);
            if (DUAL) {
                short8 b20 = *(const short8*)&B2s[(wc * 32 + ml) * NSLD + ko];
                short8 b21 = *(const short8*)&B2s[(wc * 32 + 16 + ml) * NSLD + ko];
                acc2[0][0] = __builtin_amdgcn_mfma_f32_16x16x32_bf16(a0, b20, acc2[0][0], 0, 0, 0);
                acc2[0][1] = __builtin_amdgcn_mfma_f32_16x16x32_bf16(a0, b21, acc2[0][1], 0, 0, 0);
                acc2[1][0] = __builtin_amdgcn_mfma_f32_16x16x32_bf16(a1, b20, acc2[1][0], 0, 0, 0);
                acc2[1][1] = __builtin_amdgcn_mfma_f32_16x16x32_bf16(a1, b21, acc2[1][1], 0, 0, 0);
            }
        }
    }
}

// epilogue: bf16(acc*sc) -> rowmajor + transposed
static __device__ __forceinline__ void ep_rm_t(ush* __restrict__ rm, ush* __restrict__ tr, long base,
                                               int tm, int tn, floatx4 (&acc)[2][2], float sc, int t) {
    int w = t >> 6, lane = t & 63;
    int wr = w >> 1, wc = w & 1, ml = lane & 15, quad = lane >> 4;
    int rowb = tm * 64 + wr * 32, colb = tn * 64 + wc * 32;
#pragma unroll
    for (int i = 0; i < 2; i++)
#pragma unroll
        for (int j = 0; j < 2; j++) {
            int col = colb + j * 16 + ml;
            int r0 = rowb + i * 16 + quad * 4;
            ush h[4];
#pragma unroll
            for (int r = 0; r < 4; r++) h[r] = f2b(acc[i][j][r] * sc);
#pragma unroll
            for (int r = 0; r < 4; r++) rm[base + (long)(r0 + r) * 256 + col] = h[r];
            ushort4v ht = { h[0], h[1], h[2], h[3] };
            *(ushort4v*)&tr[base + (long)col * 256 + r0] = ht;
        }
}

__global__ __launch_bounds__(256, 1) void ns_mega(NSArgs a) {
    __shared__ __align__(16) ush SM[3 * 64 * NSLD];   // 52224 B
    ush* As  = SM;
    ush* B1s = SM + 64 * NSLD;
    ush* B2s = SM + 2 * 64 * NSLD;
    cg::grid_group grid = cg::this_grid();
    int b = blockIdx.x;
    int t = threadIdx.x, lane = t & 63, wid = t >> 6;
    int g = b >> 4, tile = b & 15, tm = tile >> 2, tn = tile & 3;
    long base = (long)g * 65536;
    floatx4 acc1[2][2], acc2[2][2];

    // ---- stage M: job A = rv_merge(b); job B = ns_prep(b)
    {
        int s = tile >> 2, mq = tile & 3;
        int d = t & 63;
        int m0 = mq * 16 + (t >> 6) * 4;
        long pb = ((long)(g * 4 + s)) * NSL;
#pragma unroll
        for (int mm = 0; mm < 4; mm++) {
            int rho = m0 + mm;
            float L = 0.f, val = 0.f;
#pragma unroll
            for (int n = 0; n < NSL; n++) {
                L   += a.Lp[(pb + n) * 64 + rho];
                val += a.RVp[(pb + n) * 4096 + (long)rho * 64 + d];
            }
            a.RVt[(long)g * 16384 + d * 256 + s * 64 + rho] = f2b(val / L);
        }
        // ns_prep: tc = tile&3, tr = tile>>2
        int tc = tile & 3, tr = tile >> 2;
        float* ftile = (float*)SM;                  // 64x65 floats = 16640 B
        float* smax  = (float*)(SM + 2 * 64 * NSLD); // 4 floats
        float v = a.colsum[g * 256 + t];
#pragma unroll
        for (int off = 32; off; off >>= 1) v = fmaxf(v, __shfl_xor(v, off));
        if (lane == 0) smax[wid] = v;
        __syncthreads();
        float sc = 1.0f / fmaxf(fmaxf(smax[0], smax[1]), fmaxf(smax[2], smax[3]));
        if (t == 0 && tile == 0) a.scale[g] = sc;
        const float* ug = a.u + base;
        int cq = (t & 15) * 4, r0 = t >> 4;
#pragma unroll
        for (int i = 0; i < 4; i++) {
            int r = r0 + 16 * i;
            float4 vv = *(const float4*)&ug[(long)(tr * 64 + r) * MSEL + tc * 64 + cq];
            long o = base + (long)(tr * 64 + r) * MSEL + tc * 64 + cq;
            ushort4v ub = { f2b(vv.x), f2b(vv.y), f2b(vv.z), f2b(vv.w) };
            *(ushort4v*)&a.u_bf[o] = ub;
            ftile[r * 65 + cq] = vv.x; ftile[r * 65 + cq + 1] = vv.y;
            ftile[r * 65 + cq + 2] = vv.z; ftile[r * 65 + cq + 3] = vv.w;
        }
        __syncthreads();
#pragma unroll
        for (int i = 0; i < 4; i++) {
            int r = r0 + 16 * i;
            ushort4v o = { f2b(sc * ftile[cq * 65 + r]), f2b(sc * ftile[(cq + 1) * 65 + r]),
                           f2b(sc * ftile[(cq + 2) * 65 + r]), f2b(sc * ftile[(cq + 3) * 65 + r]) };
            *(ushort4v*)&a.Va[base + (long)(tc * 64 + r) * MSEL + tr * 64 + cq] = o;
        }
    }
    grid.sync();

    // ---- stage E0: E = sc * u @ u^T
    {
#pragma unroll
        for (int i = 0; i < 2; i++)
#pragma unroll
            for (int j = 0; j < 2; j++) acc1[i][j] = floatx4{0.f, 0.f, 0.f, 0.f};
        mm_core<false>(a.u_bf + base + (long)tm * 64 * 256, a.u_bf + base + (long)tn * 64 * 256,
                       (const ush*)0, As, B1s, B2s, acc1, acc2, t);
        ep_rm_t(a.E_a, a.Et_a, base, tm, tn, acc1, a.scale[g], t);
    }
    grid.sync();

    // ---- stage S0: S = E @ E
    {
#pragma unroll
        for (int i = 0; i < 2; i++)
#pragma unroll
            for (int j = 0; j < 2; j++) acc1[i][j] = floatx4{0.f, 0.f, 0.f, 0.f};
        mm_core<false>(a.E_a + base + (long)tm * 64 * 256, a.Et_a + base + (long)tn * 64 * 256,
                       (const ush*)0, As, B1s, B2s, acc1, acc2, t);
        ep_rm_t(a.S, a.St, base, tm, tn, acc1, 1.0f, t);
    }
    grid.sync();

    ush* E = a.E_a;  ush* Et = a.Et_a;
    ush* En = a.E_b; ush* Ent = a.Et_b;
    ush* Vc = a.Va;  ush* Vn = a.Vb;
    int w = t >> 6;
    int wr = w >> 1, wc = w & 1, ml = lane & 15, quad = lane >> 4;
    for (int it = 0; it < 3; it++) {
        // ---- stage C: acc1 = S@E, acc2 = S@S -> E' (En rm+t), P (Pt)
#pragma unroll
        for (int i = 0; i < 2; i++)
#pragma unroll
            for (int j = 0; j < 2; j++) { acc1[i][j] = floatx4{0.f,0.f,0.f,0.f}; acc2[i][j] = floatx4{0.f,0.f,0.f,0.f}; }
        mm_core<true>(a.S + base + (long)tm * 64 * 256, Et + base + (long)tn * 64 * 256,
                      a.St + base + (long)tn * 64 * 256, As, B1s, B2s, acc1, acc2, t);
        {
            int rowb = tm * 64 + wr * 32, colb = tn * 64 + wc * 32;
#pragma unroll
            for (int i = 0; i < 2; i++)
#pragma unroll
                for (int j = 0; j < 2; j++) {
                    int col = colb + j * 16 + ml;
                    int r0 = rowb + i * 16 + quad * 4;
                    ushort4v et = *(const ushort4v*)&Et[base + (long)col * 256 + r0];
                    ushort4v st = *(const ushort4v*)&a.St[base + (long)col * 256 + r0];
                    ushort4v pv;
                    ush h[4];
#pragma unroll
                    for (int r = 0; r < 4; r++) {
                        float e = b2f(et[r]), s = b2f(st[r]);
                        float p = 0.25f * (((r0 + r == col) ? 13.0f : 0.0f) - 15.0f * e + 7.0f * s - acc1[i][j][r]);
                        pv[r] = f2b(p);
                        float en = 0.25f * (13.0f * e - 15.0f * s + 7.0f * acc1[i][j][r] - acc2[i][j][r]);
                        h[r] = f2b(en);
                    }
                    *(ushort4v*)&a.Pt[base + (long)col * 256 + r0] = pv;
#pragma unroll
                    for (int r = 0; r < 4; r++) En[base + (long)(r0 + r) * 256 + col] = h[r];
                    ushort4v ht = { h[0], h[1], h[2], h[3] };
                    *(ushort4v*)&Ent[base + (long)col * 256 + r0] = ht;
                }
        }
        grid.sync();
        // ---- stage D: job0 S' = E'@E' ; job1 V' = Vc@P
#pragma unroll
        for (int i = 0; i < 2; i++)
#pragma unroll
            for (int j = 0; j < 2; j++) acc1[i][j] = floatx4{0.f,0.f,0.f,0.f};
        mm_core<false>(En + base + (long)tm * 64 * 256, Ent + base + (long)tn * 64 * 256,
                       (const ush*)0, As, B1s, B2s, acc1, acc2, t);
        ep_rm_t(a.S, a.St, base, tm, tn, acc1, 1.0f, t);
#pragma unroll
        for (int i = 0; i < 2; i++)
#pragma unroll
            for (int j = 0; j < 2; j++) acc1[i][j] = floatx4{0.f,0.f,0.f,0.f};
        mm_core<false>(Vc + base + (long)tm * 64 * 256, a.Pt + base + (long)tn * 64 * 256,
                       (const ush*)0, As, B1s, B2s, acc1, acc2, t);
        {
            int rowb = tm * 64 + wr * 32, colb = tn * 64 + wc * 32;
#pragma unroll
            for (int i = 0; i < 2; i++)
#pragma unroll
                for (int j = 0; j < 2; j++) {
                    int col = colb + j * 16 + ml;
                    int r0 = rowb + i * 16 + quad * 4;
#pragma unroll
                    for (int r = 0; r < 4; r++) Vn[base + (long)(r0 + r) * 256 + col] = f2b(acc1[i][j][r]);
                }
        }
        grid.sync();
        ush* tp;
        tp = E; E = En; En = tp;
        tp = Et; Et = Ent; Ent = tp;
        tp = Vc; Vc = Vn; Vn = tp;
    }

    // ---- stage P3: acc1 = S@E -> P only
    {
#pragma unroll
        for (int i = 0; i < 2; i++)
#pragma unroll
            for (int j = 0; j < 2; j++) acc1[i][j] = floatx4{0.f,0.f,0.f,0.f};
        mm_core<false>(a.S + base + (long)tm * 64 * 256, Et + base + (long)tn * 64 * 256,
                       (const ush*)0, As, B1s, B2s, acc1, acc2, t);
        int rowb = tm * 64 + wr * 32, colb = tn * 64 + wc * 32;
#pragma unroll
        for (int i = 0; i < 2; i++)
#pragma unroll
            for (int j = 0; j < 2; j++) {
                int col = colb + j * 16 + ml;
                int r0 = rowb + i * 16 + quad * 4;
                ushort4v et = *(const ushort4v*)&Et[base + (long)col * 256 + r0];
                ushort4v st = *(const ushort4v*)&a.St[base + (long)col * 256 + r0];
                ushort4v pv;
#pragma unroll
                for (int r = 0; r < 4; r++) {
                    float e = b2f(et[r]), s = b2f(st[r]);
                    pv[r] = f2b(0.25f * (((r0 + r == col) ? 13.0f : 0.0f) - 15.0f * e + 7.0f * s - acc1[i][j][r]));
                }
                *(ushort4v*)&a.Pt[base + (long)col * 256 + r0] = pv;
            }
    }
    grid.sync();

    // ---- stage V4: V4 = V3 @ P3 -> Vn (rm only)
    {
#pragma unroll
        for (int i = 0; i < 2; i++)
#pragma unroll
            for (int j = 0; j < 2; j++) acc1[i][j] = floatx4{0.f,0.f,0.f,0.f};
        mm_core<false>(Vc + base + (long)tm * 64 * 256, a.Pt + base + (long)tn * 64 * 256,
                       (const ush*)0, As, B1s, B2s, acc1, acc2, t);
        int rowb = tm * 64 + wr * 32, colb = tn * 64 + wc * 32;
#pragma unroll
        for (int i = 0; i < 2; i++)
#pragma unroll
            for (int j = 0; j < 2; j++) {
                int col = colb + j * 16 + ml;
                int r0 = rowb + i * 16 + quad * 4;
#pragma unroll
                for (int r = 0; r < 4; r++) Vn[base + (long)(r0 + r) * 256 + col] = f2b(acc1[i][j][r]);
            }
    }
    grid.sync();

    // ---- stage W (64 blocks): Wt hi/lo = (V4 @ RV)^T
    if (b < 64) {
        int gw = b >> 2, tmw = b & 3;
        long bw = (long)gw * 65536;
#pragma unroll
        for (int i = 0; i < 2; i++)
#pragma unroll
            for (int j = 0; j < 2; j++) acc1[i][j] = floatx4{0.f,0.f,0.f,0.f};
        mm_core<false>(Vn + bw + (long)tmw * 64 * 256, a.RVt + (long)gw * 16384,
                       (const ush*)0, As, B1s, B2s, acc1, acc2, t);
        int rowb = tmw * 64 + wr * 32, colb = wc * 32;
#pragma unroll
        for (int i = 0; i < 2; i++)
#pragma unroll
            for (int j = 0; j < 2; j++) {
                int col = colb + j * 16 + ml;
                int r0 = rowb + i * 16 + quad * 4;
                ushort4v hv, lv;
#pragma unroll
                for (int r = 0; r < 4; r++) {
                    float v = acc1[i][j][r];
                    ush h = f2b(v);
                    hv[r] = h;
                    lv[r] = f2b(v - b2f(h));
                }
                *(ushort4v*)&a.WtH[(long)gw * 16384 + (long)col * 256 + r0] = hv;
                *(ushort4v*)&a.WtL[(long)gw * 16384 + (long)col * 256 + r0] = lv;
            }
    }
}

extern "C" void kernel_launch(void* const* d_in, const int* in_sizes, int n_in,
                              void* d_out, int out_size, void* d_ws, size_t ws_size,
                              hipStream_t stream) {
    (void)in_sizes; (void)n_in; (void)out_size; (void)ws_size;
    const float* Q = (const float*)d_in[0];
    const float* K = (const float*)d_in[1];
    const float* V = (const float*)d_in[2];

    float* ws    = (float*)d_ws;
    float* sumQ  = ws;
    float* sumK  = sumQ + 65536;
    float* k2    = sumK + 65536;
    float* nr    = k2 + 65536;
    float* u     = nr + 262144;
    float* Mb    = u + 1048576;
    float* Kmax2 = Mb + 4096;
    float* scale = Kmax2 + 16;
    float* colsum= scale + 16 + 32;
    float* Lp    = colsum + 4096;
    float* RVp   = Lp + 65536;
    int* idxQ    = (int*)(RVp + 4194304);
    int* idxK    = idxQ + 4096;
    ush* ncH     = (ush*)(idxK + 4096);
    ush* ncL     = ncH + 262144;
    ush* WtH     = ncL + 262144;
    ush* WtL     = WtH + 262144;
    ush* RVt     = WtL + 262144;
    ush* u_bf    = RVt + 262144;
    ush* Vacc_a  = u_bf + 1048576;
    ush* Vacc_b  = Vacc_a + 1048576;
    ush* E_a     = Vacc_b + 1048576;
    ush* Et_a    = E_a + 1048576;
    ush* E_b     = Et_a + 1048576;
    ush* Et_b    = E_b + 1048576;
    ush* Sbuf    = Et_b + 1048576;
    ush* St      = Sbuf + 1048576;
    ush* Ptb     = St + 1048576;

    dim3 blk(256);

    hipLaunchKernelGGL(rowsum_kernel, dim3(G * NSEQ / 16), blk, 0, stream, Q, K, sumQ, sumK, k2);
    hipLaunchKernelGGL(topk_select, dim3(G, 2), blk, 0, stream, sumQ, sumK, idxQ, idxK, k2, Kmax2, colsum);
    hipLaunchKernelGGL(gather_kernel, dim3(G * MSEL / 4), blk, 0, stream, Q, K, idxQ, idxK, Kmax2, nr, ncH, ncL, Mb);

    hipLaunchKernelGGL(flash_rv, dim3(NSL, 4, G), blk, 0, stream, nr, K, V, Mb, Lp, RVp);

    hipLaunchKernelGGL((fused_cx<1>), dim3(4, G), blk, 0, stream, nr, ncH, ncL,
                       (const ush*)0, (const ush*)0, u, colsum, 1.0f);

    // cooperative NS: mergeprep + E0,S0,(C,D)x3,P3,V4,W with 11 grid syncs
    NSArgs nsa;
    nsa.Lp = Lp; nsa.RVp = RVp; nsa.RVt = RVt;
    nsa.u = u; nsa.colsum = colsum;
    nsa.u_bf = u_bf; nsa.scale = scale;
    nsa.Va = Vacc_a; nsa.Vb = Vacc_b;
    nsa.E_a = E_a; nsa.Et_a = Et_a; nsa.E_b = E_b; nsa.Et_b = Et_b;
    nsa.S = Sbuf; nsa.St = St; nsa.Pt = Ptb;
    nsa.WtH = WtH; nsa.WtL = WtL;
    void* kargs[] = { (void*)&nsa };
    hipLaunchCooperativeKernel((const void*)ns_mega, dim3(256), dim3(256), kargs, 0, stream);

    hipLaunchKernelGGL((fused_cx<0>), dim3(64, G), blk, 0, stream, Q, ncH, ncL, WtH, WtL,
                       (float*)d_out, (float*)0, 0.125f);
}

// Round 11
// 255.493 us; speedup vs baseline: 2.4133x; 2.4133x over previous
//
#include <hip/hip_runtime.h>
#include <float.h>

// CURAttention MI355X — Round 11: REVERT to R9 structure.
// R10 post-mortem: hipLaunchCooperativeKernel grid.sync() measured ~35us each
// on MI355X (8 non-coherent XCDs -> L3/HBM-scope barrier) vs ~1.75us per
// kernel-launch boundary. The 18-dispatch R9 chain IS the cheap expression.
// NS: P_i=0.25(13I-15E+7S-S@E); E'=0.25(13E-15S+7S@E-S@S); batched {S',V'}.

#define G    16
#define NSEQ 4096
#define DH   64
#define MSEL 256
#define NSL  16

typedef __attribute__((ext_vector_type(8))) short short8;
typedef __attribute__((ext_vector_type(4))) float floatx4;
typedef __attribute__((ext_vector_type(4))) unsigned short ushort4v;
typedef unsigned short ush;

static __device__ __forceinline__ ush f2b(float x) {
    union { float f; unsigned u; } c{x};
    unsigned r = c.u + 0x7FFFu + ((c.u >> 16) & 1u);   // RNE
    return (ush)(r >> 16);
}
static __device__ __forceinline__ float b2f(ush h) {
    union { unsigned u; float f; } c{(unsigned)h << 16};
    return c.f;
}
static __device__ __forceinline__ void split_store(ush* __restrict__ h, ush* __restrict__ l,
                                                   int off, float4 v, float scale) {
    float a0 = v.x * scale, a1 = v.y * scale, a2 = v.z * scale, a3 = v.w * scale;
    ush h0 = f2b(a0), h1 = f2b(a1), h2 = f2b(a2), h3 = f2b(a3);
    ushort4v hv = { h0, h1, h2, h3 };
    ushort4v lv = { f2b(a0 - b2f(h0)), f2b(a1 - b2f(h1)), f2b(a2 - b2f(h2)), f2b(a3 - b2f(h3)) };
    *(ushort4v*)&h[off] = hv;
    *(ushort4v*)&l[off] = lv;
}
static __device__ __forceinline__ floatx4 mfma3(short8 ah, short8 al, short8 bh, short8 bl, floatx4 acc) {
    acc = __builtin_amdgcn_mfma_f32_16x16x32_bf16(al, bh, acc, 0, 0, 0);
    acc = __builtin_amdgcn_mfma_f32_16x16x32_bf16(ah, bl, acc, 0, 0, 0);
    acc = __builtin_amdgcn_mfma_f32_16x16x32_bf16(ah, bh, acc, 0, 0, 0);
    return acc;
}

// ---------------- row sums + K row-norm^2 ----------------
__global__ __launch_bounds__(256) void rowsum_kernel(const float* __restrict__ Q, const float* __restrict__ K,
                                                     float* __restrict__ sumQ, float* __restrict__ sumK,
                                                     float* __restrict__ k2) {
    long row = (long)blockIdx.x * 16 + (threadIdx.x >> 4);
    int c4 = (threadIdx.x & 15) * 4;
    float4 q = *(const float4*)(Q + row * DH + c4);
    float4 k = *(const float4*)(K + row * DH + c4);
    float qs = q.x + q.y + q.z + q.w;
    float ks = k.x + k.y + k.z + k.w;
    float k2s = k.x * k.x + k.y * k.y + k.z * k.z + k.w * k.w;
#pragma unroll
    for (int off = 8; off; off >>= 1) {
        qs += __shfl_xor(qs, off); ks += __shfl_xor(ks, off); k2s += __shfl_xor(k2s, off);
    }
    if ((threadIdx.x & 15) == 0) { sumQ[row] = qs; sumK[row] = ks; k2[row] = k2s; }
}

// ---------------- top-256 + per-g max K-norm^2 + colsum zero ----------------
__global__ __launch_bounds__(256) void topk_select(const float* __restrict__ sumQ, const float* __restrict__ sumK,
                                                   int* __restrict__ idxQ, int* __restrict__ idxK,
                                                   const float* __restrict__ k2, float* __restrict__ Kmax2,
                                                   float* __restrict__ colsum) {
    __shared__ unsigned red[4];
    __shared__ float redf[4];
    __shared__ unsigned eqpre[64];
    __shared__ unsigned cnt_sel;
    int g = blockIdx.x, which = blockIdx.y;
    const float* s = (which ? sumK : sumQ) + (long)g * NSEQ;
    int* out = (which ? idxK : idxQ) + g * MSEL;
    int t = threadIdx.x, lane = t & 63, wid = t >> 6;
    if (which == 0) colsum[g * 256 + t] = 0.f;
    unsigned k[16];
#pragma unroll
    for (int i = 0; i < 16; i++) {
        unsigned u = __float_as_uint(s[t + 256 * i]);
        k[i] = (u & 0x80000000u) ? ~u : (u | 0x80000000u);
    }
    unsigned T = 0;
    for (int b = 31; b >= 0; b--) {
        unsigned trial = T | (1u << b);
        int c = 0;
#pragma unroll
        for (int i = 0; i < 16; i++) c += (k[i] >= trial);
#pragma unroll
        for (int off = 32; off; off >>= 1) c += __shfl_xor(c, off);
        __syncthreads();
        if (lane == 0) red[wid] = (unsigned)c;
        __syncthreads();
        unsigned tot = red[0] + red[1] + red[2] + red[3];
        if (tot == MSEL) { T = trial; break; }
        if (tot > MSEL) T = trial;
    }
    int cg = 0;
#pragma unroll
    for (int i = 0; i < 16; i++) cg += (k[i] > T);
#pragma unroll
    for (int off = 32; off; off >>= 1) cg += __shfl_xor(cg, off);
    __syncthreads();
    if (lane == 0) red[wid] = (unsigned)cg;
    if (t == 0) cnt_sel = 0;
    __syncthreads();
    unsigned ngreater = red[0] + red[1] + red[2] + red[3];
    unsigned want_eq = MSEL - ngreater;
#pragma unroll
    for (int i = 0; i < 16; i++) {
        unsigned long long be = __ballot(k[i] == T);
        if (lane == 0) eqpre[i * 4 + wid] = (unsigned)__popcll(be);
    }
    __syncthreads();
    if (t == 0) {
        unsigned run = 0;
        for (int j = 0; j < 64; j++) { unsigned c = eqpre[j]; eqpre[j] = run; run += c; }
    }
    __syncthreads();
#pragma unroll
    for (int i = 0; i < 16; i++) {
        int idx = t + 256 * i;
        unsigned long long lt = (1ull << lane) - 1;
        bool gt = (k[i] > T);
        unsigned long long bg = __ballot(gt);
        unsigned wbase = 0;
        if (lane == 0) wbase = atomicAdd(&cnt_sel, (unsigned)__popcll(bg));
        wbase = __shfl((int)wbase, 0);
        if (gt) out[wbase + __popcll(bg & lt)] = idx;
        bool eq = (k[i] == T);
        unsigned long long be = __ballot(eq);
        if (eq) {
            unsigned rank = eqpre[i * 4 + wid] + (unsigned)__popcll(be & lt);
            if (rank < want_eq) out[ngreater + rank] = idx;
        }
    }
    if (which == 1) {
        float mx = 0.f;
#pragma unroll
        for (int i = 0; i < 16; i++) mx = fmaxf(mx, k2[(long)g * NSEQ + t + 256 * i]);
#pragma unroll
        for (int off = 32; off; off >>= 1) mx = fmaxf(mx, __shfl_xor(mx, off));
        __syncthreads();
        if (lane == 0) redf[wid] = mx;
        __syncthreads();
        if (t == 0) Kmax2[g] = fmaxf(fmaxf(redf[0], redf[1]), fmaxf(redf[2], redf[3]));
    }
}

// ---------------- gather ----------------
__global__ __launch_bounds__(256) void gather_kernel(const float* __restrict__ Q, const float* __restrict__ K,
                                                     const int* __restrict__ idxQ, const int* __restrict__ idxK,
                                                     const float* __restrict__ Kmax2,
                                                     float* __restrict__ nr,
                                                     ush* __restrict__ ncH, ush* __restrict__ ncL,
                                                     float* __restrict__ Mb) {
    int wid = threadIdx.x >> 6, lane = threadIdx.x & 63;
    long t = (long)blockIdx.x * 4 + wid;
    long g = t >> 8;
    int iq = idxQ[t], ik = idxK[t];
    float qv = Q[(g * NSEQ + iq) * DH + lane] * 0.125f;
    nr[t * DH + lane] = qv;
    float kv = K[(g * NSEQ + ik) * DH + lane];
    ush h = f2b(kv);
    ncH[t * DH + lane] = h;
    ncL[t * DH + lane] = f2b(kv - b2f(h));
    float n2 = qv * qv;
#pragma unroll
    for (int off = 32; off; off >>= 1) n2 += __shfl_xor(n2, off);
    if (lane == 0) Mb[t] = sqrtf(n2 * Kmax2[g]);
}

// ---------------- flash r->exp(S-M)->RV partial sums ----------------
__global__ __launch_bounds__(256, 4) void flash_rv(const float* __restrict__ nr, const float* __restrict__ K,
                                                   const float* __restrict__ V, const float* __restrict__ Mb,
                                                   float* __restrict__ Lp, float* __restrict__ RVp) {
    __shared__ __align__(16) ush B1h[64 * 72];
    __shared__ __align__(16) ush B1l[64 * 72];
    __shared__ __align__(16) ush Ph[64 * 72];
    __shared__ float msh[64];
    __shared__ float lred[64][2];
    int ns = blockIdx.x, s = blockIdx.y, g = blockIdx.z;
    int t = threadIdx.x, lane = t & 63, w = t >> 6;
    int wr = w >> 1, wc = w & 1, ml = lane & 15, quad = lane >> 4;
    int lr = t >> 2, lq = t & 3;
    const float* nrg = nr + (long)g * 16384 + (long)s * 64 * 64;
    const float* Kg  = K + (long)g * 262144 + (long)ns * 256 * 64;
    const float* Vg  = V + (long)g * 262144 + (long)ns * 256 * 64;
    short8 Ah[2][2], Al[2][2];
#pragma unroll
    for (int i2 = 0; i2 < 2; i2++)
#pragma unroll
        for (int kq = 0; kq < 2; kq++) {
            const float* p = nrg + (wr * 32 + i2 * 16 + ml) * 64 + kq * 32 + quad * 8;
            float4 f0 = *(const float4*)p;
            float4 f1 = *(const float4*)(p + 4);
            float vals[8] = { f0.x, f0.y, f0.z, f0.w, f1.x, f1.y, f1.z, f1.w };
            short8 hh, ll;
#pragma unroll
            for (int j = 0; j < 8; j++) {
                ush h = f2b(vals[j]);
                hh[j] = (short)h;
                ll[j] = (short)f2b(vals[j] - b2f(h));
            }
            Ah[i2][kq] = hh; Al[i2][kq] = ll;
        }
    if (t < 64) msh[t] = Mb[g * 256 + s * 64 + t];
    float lsum[2][4] = {};
    floatx4 acc[2][2] = {};
    int vn = t >> 2, vdq = (t & 3) * 16;
    for (int it = 0; it < 4; it++) {
        __syncthreads();
        float4 kv[4], vv[4];
#pragma unroll
        for (int q = 0; q < 4; q++) kv[q] = *(const float4*)(Kg + (long)(it * 64 + lr) * 64 + lq * 16 + q * 4);
#pragma unroll
        for (int q = 0; q < 4; q++) vv[q] = *(const float4*)(Vg + (long)(it * 64 + vn) * 64 + vdq + q * 4);
#pragma unroll
        for (int q = 0; q < 4; q++) split_store(B1h, B1l, lr * 72 + lq * 16 + q * 4, kv[q], 1.0f);
        __syncthreads();
        floatx4 sa[2][2] = {};
#pragma unroll
        for (int kq = 0; kq < 2; kq++) {
            short8 b0h = *(const short8*)&B1h[(wc * 32 + ml) * 72 + kq * 32 + quad * 8];
            short8 b0l = *(const short8*)&B1l[(wc * 32 + ml) * 72 + kq * 32 + quad * 8];
            short8 b1h = *(const short8*)&B1h[(wc * 32 + 16 + ml) * 72 + kq * 32 + quad * 8];
            short8 b1l = *(const short8*)&B1l[(wc * 32 + 16 + ml) * 72 + kq * 32 + quad * 8];
            sa[0][0] = mfma3(Ah[0][kq], Al[0][kq], b0h, b0l, sa[0][0]);
            sa[0][1] = mfma3(Ah[0][kq], Al[0][kq], b1h, b1l, sa[0][1]);
            sa[1][0] = mfma3(Ah[1][kq], Al[1][kq], b0h, b0l, sa[1][0]);
            sa[1][1] = mfma3(Ah[1][kq], Al[1][kq], b1h, b1l, sa[1][1]);
        }
        __syncthreads();
#pragma unroll
        for (int i2 = 0; i2 < 2; i2++)
#pragma unroll
            for (int r = 0; r < 4; r++) {
                int row = wr * 32 + i2 * 16 + quad * 4 + r;
                float M = msh[row];
                float p0 = __expf(sa[i2][0][r] - M);
                float p1 = __expf(sa[i2][1][r] - M);
                lsum[i2][r] += p0 + p1;
                Ph[row * 72 + wc * 32 + ml] = f2b(p0);
                Ph[row * 72 + wc * 32 + 16 + ml] = f2b(p1);
            }
#pragma unroll
        for (int q = 0; q < 4; q++)
#pragma unroll
            for (int c = 0; c < 4; c++) {
                int d = vdq + q * 4 + c;
                int addr = d * 72 + ((((vn >> 3) ^ ((d >> 4) & 3)) << 3) | (vn & 7));
                B1h[addr] = f2b((&vv[q].x)[c]);
            }
        __syncthreads();
#pragma unroll
        for (int kq = 0; kq < 2; kq++) {
            short8 a0 = *(const short8*)&Ph[(wr * 32 + ml) * 72 + kq * 32 + quad * 8];
            short8 a1 = *(const short8*)&Ph[(wr * 32 + 16 + ml) * 72 + kq * 32 + quad * 8];
            int nb = kq * 4 + quad;
            short8 b0 = *(const short8*)&B1h[(wc * 32 + ml) * 72 + ((nb ^ (2 * wc)) << 3)];
            short8 b1 = *(const short8*)&B1h[(wc * 32 + 16 + ml) * 72 + ((nb ^ (2 * wc + 1)) << 3)];
            acc[0][0] = __builtin_amdgcn_mfma_f32_16x16x32_bf16(a0, b0, acc[0][0], 0, 0, 0);
            acc[0][1] = __builtin_amdgcn_mfma_f32_16x16x32_bf16(a0, b1, acc[0][1], 0, 0, 0);
            acc[1][0] = __builtin_amdgcn_mfma_f32_16x16x32_bf16(a1, b0, acc[1][0], 0, 0, 0);
            acc[1][1] = __builtin_amdgcn_mfma_f32_16x16x32_bf16(a1, b1, acc[1][1], 0, 0, 0);
        }
    }
#pragma unroll
    for (int i2 = 0; i2 < 2; i2++)
#pragma unroll
        for (int r = 0; r < 4; r++) {
            float v = lsum[i2][r];
#pragma unroll
            for (int off = 8; off; off >>= 1) v += __shfl_xor(v, off);
            if (ml == 0) lred[wr * 32 + i2 * 16 + quad * 4 + r][wc] = v;
        }
    __syncthreads();
    long p = ((long)(g * 4 + s)) * NSL + ns;
    if (t < 64) Lp[p * 64 + t] = lred[t][0] + lred[t][1];
    float* rvp = RVp + p * 4096;
#pragma unroll
    for (int i2 = 0; i2 < 2; i2++)
#pragma unroll
        for (int j2 = 0; j2 < 2; j2++)
#pragma unroll
            for (int r = 0; r < 4; r++)
                rvp[(wr * 32 + i2 * 16 + quad * 4 + r) * 64 + wc * 32 + j2 * 16 + ml] = acc[i2][j2][r];
}

// ---------------- fused c -> softmax -> (X | u + colsum) ----------------
template <int MODE>
__global__ __launch_bounds__(256, 4) void fused_cx(const float* __restrict__ A,
                                                   const ush* __restrict__ ncH, const ush* __restrict__ ncL,
                                                   const ush* __restrict__ WtH, const ush* __restrict__ WtL,
                                                   float* __restrict__ Out, float* __restrict__ colsum,
                                                   float ascale) {
    __shared__ __align__(16) ush SM[18432];
    ush* Ah = SM;            ush* Al = SM + 4608;
    ush* Bh = SM + 9216;     ush* Bl = SM + 13824;
    ush* Ph = SM;            ush* Pl = SM + 4608;
    ush* Wh = SM + 9216;     ush* Wl = SM + 13824;
    __shared__ float pm[256], ps[256], Mr[64], Lr[64];
    int strip = blockIdx.x, g = blockIdx.y;
    int t = threadIdx.x, lane = t & 63, w = t >> 6;
    int wr = w >> 1, wc = w & 1, ml = lane & 15, quad = lane >> 4;
    int lr = t >> 2, lq = t & 3;
    long aRows = (MODE == 0) ? 4096 : 256;
    const float* Ag = A + (long)g * aRows * 64 + (long)strip * 64 * 64;
    const ush* ncHg = ncH + (long)g * 16384;
    const ush* ncLg = ncL + (long)g * 16384;
#pragma unroll
    for (int q = 0; q < 4; q++) {
        float4 v = *(const float4*)(Ag + lr * 64 + lq * 16 + q * 4);
        split_store(Ah, Al, lr * 72 + lq * 16 + q * 4, v, ascale);
    }
    floatx4 sacc[4][4] = {};
    for (int c = 0; c < 4; c++) {
        __syncthreads();
        {
            const ush* sH = ncHg + (c * 64 + lr) * 64;
            const ush* sL = ncLg + (c * 64 + lr) * 64;
            *(uint4*)&Bh[lr * 72 + lq * 8]       = *(const uint4*)&sH[lq * 8];
            *(uint4*)&Bh[lr * 72 + (lq + 4) * 8] = *(const uint4*)&sH[(lq + 4) * 8];
            *(uint4*)&Bl[lr * 72 + lq * 8]       = *(const uint4*)&sL[lq * 8];
            *(uint4*)&Bl[lr * 72 + (lq + 4) * 8] = *(const uint4*)&sL[(lq + 4) * 8];
        }
        __syncthreads();
#pragma unroll
        for (int kq = 0; kq < 2; kq++) {
            short8 bh = *(const short8*)&Bh[(w * 16 + ml) * 72 + kq * 32 + quad * 8];
            short8 bl = *(const short8*)&Bl[(w * 16 + ml) * 72 + kq * 32 + quad * 8];
#pragma unroll
            for (int i = 0; i < 4; i++) {
                short8 afh = *(const short8*)&Ah[(16 * i + ml) * 72 + kq * 32 + quad * 8];
                short8 afl = *(const short8*)&Al[(16 * i + ml) * 72 + kq * 32 + quad * 8];
                sacc[c][i] = mfma3(afh, afl, bh, bl, sacc[c][i]);
            }
        }
    }
#pragma unroll
    for (int i = 0; i < 4; i++)
#pragma unroll
        for (int r = 0; r < 4; r++) {
            float mx = fmaxf(fmaxf(sacc[0][i][r], sacc[1][i][r]), fmaxf(sacc[2][i][r], sacc[3][i][r]));
#pragma unroll
            for (int off = 8; off; off >>= 1) mx = fmaxf(mx, __shfl_xor(mx, off));
            if (ml == 0) pm[(16 * i + quad * 4 + r) * 4 + w] = mx;
        }
    __syncthreads();
    if (t < 64) Mr[t] = fmaxf(fmaxf(pm[t * 4], pm[t * 4 + 1]), fmaxf(pm[t * 4 + 2], pm[t * 4 + 3]));
    __syncthreads();
#pragma unroll
    for (int i = 0; i < 4; i++)
#pragma unroll
        for (int r = 0; r < 4; r++) {
            int row = 16 * i + quad * 4 + r;
            float M = Mr[row];
            float sum = 0.f;
#pragma unroll
            for (int c = 0; c < 4; c++) {
                float p = __expf(sacc[c][i][r] - M);
                sacc[c][i][r] = p;
                sum += p;
            }
#pragma unroll
            for (int off = 8; off; off >>= 1) sum += __shfl_xor(sum, off);
            if (ml == 0) ps[row * 4 + w] = sum;
        }
    __syncthreads();
    if (t < 64) Lr[t] = ps[t * 4] + ps[t * 4 + 1] + ps[t * 4 + 2] + ps[t * 4 + 3];
    __syncthreads();
    if (MODE == 1) {
        float invL[4][4];
#pragma unroll
        for (int i = 0; i < 4; i++)
#pragma unroll
            for (int r = 0; r < 4; r++) invL[i][r] = 1.0f / Lr[16 * i + quad * 4 + r];
        float* ug = Out + (long)g * 65536 + (long)strip * 64 * 256;
#pragma unroll
        for (int i = 0; i < 4; i++)
#pragma unroll
            for (int r = 0; r < 4; r++) {
                int row = 16 * i + quad * 4 + r;
#pragma unroll
                for (int c = 0; c < 4; c++)
                    ug[(long)row * 256 + c * 64 + w * 16 + ml] = sacc[c][i][r] * invL[i][r];
            }
#pragma unroll
        for (int c = 0; c < 4; c++) {
            float v = 0.f;
#pragma unroll
            for (int i = 0; i < 4; i++)
#pragma unroll
                for (int r = 0; r < 4; r++) v += sacc[c][i][r] * invL[i][r];
            v += __shfl_xor(v, 16);
            v += __shfl_xor(v, 32);
            if (quad == 0) atomicAdd(&colsum[g * 256 + c * 64 + w * 16 + ml], v);
        }
        return;
    }
    floatx4 xacc[2][2] = {};
    const ush* wHg = WtH + (long)g * 16384;
    const ush* wLg = WtL + (long)g * 16384;
#pragma unroll
    for (int h = 0; h < 4; h++) {
        __syncthreads();
#pragma unroll
        for (int i = 0; i < 4; i++)
#pragma unroll
            for (int r = 0; r < 4; r++) {
                int row = 16 * i + quad * 4 + r;
                float p = sacc[h][i][r];
                ush hh = f2b(p);
                Ph[row * 72 + w * 16 + ml] = hh;
                Pl[row * 72 + w * 16 + ml] = f2b(p - b2f(hh));
            }
        {
            const ush* sH = wHg + lr * 256 + h * 64;
            const ush* sL = wLg + lr * 256 + h * 64;
            *(uint4*)&Wh[lr * 72 + lq * 8]       = *(const uint4*)&sH[lq * 8];
            *(uint4*)&Wh[lr * 72 + (lq + 4) * 8] = *(const uint4*)&sH[(lq + 4) * 8];
            *(uint4*)&Wl[lr * 72 + lq * 8]       = *(const uint4*)&sL[lq * 8];
            *(uint4*)&Wl[lr * 72 + (lq + 4) * 8] = *(const uint4*)&sL[(lq + 4) * 8];
        }
        __syncthreads();
#pragma unroll
        for (int kq = 0; kq < 2; kq++) {
            short8 a0h = *(const short8*)&Ph[(wr * 32 + ml) * 72 + kq * 32 + quad * 8];
            short8 a0l = *(const short8*)&Pl[(wr * 32 + ml) * 72 + kq * 32 + quad * 8];
            short8 a1h = *(const short8*)&Ph[(wr * 32 + 16 + ml) * 72 + kq * 32 + quad * 8];
            short8 a1l = *(const short8*)&Pl[(wr * 32 + 16 + ml) * 72 + kq * 32 + quad * 8];
            short8 b0h = *(const short8*)&Wh[(wc * 32 + ml) * 72 + kq * 32 + quad * 8];
            short8 b0l = *(const short8*)&Wl[(wc * 32 + ml) * 72 + kq * 32 + quad * 8];
            short8 b1h = *(const short8*)&Wh[(wc * 32 + 16 + ml) * 72 + kq * 32 + quad * 8];
            short8 b1l = *(const short8*)&Wl[(wc * 32 + 16 + ml) * 72 + kq * 32 + quad * 8];
            xacc[0][0] = mfma3(a0h, a0l, b0h, b0l, xacc[0][0]);
            xacc[0][1] = mfma3(a0h, a0l, b1h, b1l, xacc[0][1]);
            xacc[1][0] = mfma3(a1h, a1l, b0h, b0l, xacc[1][0]);
            xacc[1][1] = mfma3(a1h, a1l, b1h, b1l, xacc[1][1]);
        }
    }
    float* outg = Out + (long)g * 262144 + (long)strip * 64 * 64;
#pragma unroll
    for (int i2 = 0; i2 < 2; i2++)
#pragma unroll
        for (int j2 = 0; j2 < 2; j2++)
#pragma unroll
            for (int r = 0; r < 4; r++) {
                int row = wr * 32 + i2 * 16 + quad * 4 + r;
                outg[(long)row * 64 + wc * 32 + j2 * 16 + ml] = xacc[i2][j2][r] / Lr[row];
            }
}

// ---------------- merged: z=0 rv_merge -> RVt; z=1 ns_prep (scale, u_bf, V0) ----------------
__global__ __launch_bounds__(256) void mergeprep_kernel(const float* __restrict__ Lp, const float* __restrict__ RVp,
                                                        ush* __restrict__ RVt,
                                                        const float* __restrict__ u, const float* __restrict__ colsum,
                                                        ush* __restrict__ u_bf, ush* __restrict__ V0,
                                                        float* __restrict__ scale) {
    __shared__ float tile[64][65];
    __shared__ float smax[4];
    int g = blockIdx.y;
    int t = threadIdx.x, lane = t & 63, wid = t >> 6;
    if (blockIdx.z == 0) {
        int s = blockIdx.x >> 2, mq = blockIdx.x & 3;
        int d = t & 63;
        int m0 = mq * 16 + (t >> 6) * 4;
        long pb = ((long)(g * 4 + s)) * NSL;
#pragma unroll
        for (int mm = 0; mm < 4; mm++) {
            int rho = m0 + mm;
            float L = 0.f, val = 0.f;
#pragma unroll
            for (int n = 0; n < NSL; n++) {
                L   += Lp[(pb + n) * 64 + rho];
                val += RVp[(pb + n) * 4096 + rho * 64 + d];
            }
            RVt[(long)g * 16384 + d * 256 + s * 64 + rho] = f2b(val / L);
        }
        return;
    }
    int tc = blockIdx.x & 3, tr = (blockIdx.x >> 2) & 3;
    float v = colsum[g * 256 + t];
#pragma unroll
    for (int off = 32; off; off >>= 1) v = fmaxf(v, __shfl_xor(v, off));
    if (lane == 0) smax[wid] = v;
    __syncthreads();
    float sc = 1.0f / fmaxf(fmaxf(smax[0], smax[1]), fmaxf(smax[2], smax[3]));
    if (t == 0 && tr == 0 && tc == 0) scale[g] = sc;
    long base = (long)g * MSEL * MSEL;
    const float* ug = u + base;
    int cq = (t & 15) * 4, r0 = t >> 4;
#pragma unroll
    for (int i = 0; i < 4; i++) {
        int r = r0 + 16 * i;
        float4 vv = *(const float4*)&ug[(long)(tr * 64 + r) * MSEL + tc * 64 + cq];
        long o = base + (long)(tr * 64 + r) * MSEL + tc * 64 + cq;
        ushort4v ub = { f2b(vv.x), f2b(vv.y), f2b(vv.z), f2b(vv.w) };
        *(ushort4v*)&u_bf[o] = ub;
        tile[r][cq] = vv.x; tile[r][cq + 1] = vv.y; tile[r][cq + 2] = vv.z; tile[r][cq + 3] = vv.w;
    }
    __syncthreads();
#pragma unroll
    for (int i = 0; i < 4; i++) {
        int r = r0 + 16 * i;
        ushort4v o = { f2b(sc * tile[cq][r]), f2b(sc * tile[cq + 1][r]),
                       f2b(sc * tile[cq + 2][r]), f2b(sc * tile[cq + 3][r]) };
        *(ushort4v*)&V0[base + (long)(tc * 64 + r) * MSEL + tr * 64 + cq] = o;
    }
}

// ---------------- nsAC: generic bf16 GEMM (K=256), z-batched 2 jobs ----------------
__global__ __launch_bounds__(256) void nsAC(const ush* __restrict__ A0, const ush* __restrict__ B0t,
                                            const ush* __restrict__ A1, const ush* __restrict__ B1t,
                                            ush* __restrict__ C0rm, ush* __restrict__ C0t,
                                            ush* __restrict__ C1rm,
                                            const float* __restrict__ scale, int whichBase) {
    const int LD = 136;
    __shared__ __align__(16) ush As[64 * LD];
    __shared__ __align__(16) ush Bs[64 * LD];
    int z = blockIdx.z, g = z & 15, which = (z >> 4) + whichBase;
    int tm = blockIdx.y, tn = blockIdx.x;
    long base = (long)g * 65536;
    const ush* Ag = (which ? A1 : A0) + base + (long)tm * 64 * 256;
    const ush* Bg = (which ? B1t : B0t) + base + (long)tn * 64 * 256;
    int t = threadIdx.x;
    int lr = t >> 2, lq = t & 3;
    int w = t >> 6, lane = t & 63;
    int wr = w >> 1, wc = w & 1;
    int ml = lane & 15, quad = lane >> 4;
    floatx4 acc[2][2] = {};
#pragma unroll
    for (int h = 0; h < 2; h++) {
        __syncthreads();
#pragma unroll
        for (int rr = 0; rr < 4; rr++) {
            int col = (lq + 4 * rr) * 8;
            *(uint4*)&As[lr * LD + col] = *(const uint4*)(Ag + lr * 256 + h * 128 + col);
            *(uint4*)&Bs[lr * LD + col] = *(const uint4*)(Bg + lr * 256 + h * 128 + col);
        }
        __syncthreads();
#pragma unroll
        for (int kq = 0; kq < 4; kq++) {
            int ko = kq * 32 + quad * 8;
            short8 a0 = *(const short8*)&As[(wr * 32 + ml) * LD + ko];
            short8 a1 = *(const short8*)&As[(wr * 32 + 16 + ml) * LD + ko];
            short8 b0 = *(const short8*)&Bs[(wc * 32 + ml) * LD + ko];
            short8 b1 = *(const short8*)&Bs[(wc * 32 + 16 + ml) * LD + ko];
            acc[0][0] = __builtin_amdgcn_mfma_f32_16x16x32_bf16(a0, b0, acc[0][0], 0, 0, 0);
            acc[0][1] = __builtin_amdgcn_mfma_f32_16x16x32_bf16(a0, b1, acc[0][1], 0, 0, 0);
            acc[1][0] = __builtin_amdgcn_mfma_f32_16x16x32_bf16(a1, b0, acc[1][0], 0, 0, 0);
            acc[1][1] = __builtin_amdgcn_mfma_f32_16x16x32_bf16(a1, b1, acc[1][1], 0, 0, 0);
        }
    }
    float sc = (which == 0 && scale) ? scale[g] : 1.0f;
    int rowb = tm * 64 + wr * 32, colb = tn * 64 + wc * 32;
#pragma unroll
    for (int i = 0; i < 2; i++) {
#pragma unroll
        for (int j = 0; j < 2; j++) {
            int col = colb + j * 16 + ml;
            int r0 = rowb + i * 16 + quad * 4;
            ush h[4];
#pragma unroll
            for (int r = 0; r < 4; r++) h[r] = f2b(acc[i][j][r] * sc);
            if (which == 0) {
#pragma unroll
                for (int r = 0; r < 4; r++) C0rm[base + (long)(r0 + r) * 256 + col] = h[r];
                ushort4v ht = { h[0], h[1], h[2], h[3] };
                *(ushort4v*)&C0t[base + (long)col * 256 + r0] = ht;
            } else {
#pragma unroll
                for (int r = 0; r < 4; r++) C1rm[base + (long)(r0 + r) * 256 + col] = h[r];
            }
        }
    }
}

// ---------------- nsB: C1=S@E, C2=S@S (shared A staging); epilogue -> E', P ----------------
template <bool FINAL>
__global__ __launch_bounds__(256) void nsB(const ush* __restrict__ S, const ush* __restrict__ Et,
                                           const ush* __restrict__ St,
                                           ush* __restrict__ Eo, ush* __restrict__ Eot,
                                           ush* __restrict__ Pt) {
    const int LD = 136;
    __shared__ __align__(16) ush As[64 * LD];
    __shared__ __align__(16) ush B1s[64 * LD];
    __shared__ __align__(16) ush B2s[64 * LD];
    int g = blockIdx.z, tm = blockIdx.y, tn = blockIdx.x;
    long base = (long)g * 65536;
    const ush* Ag  = S + base + (long)tm * 64 * 256;
    const ush* B1g = Et + base + (long)tn * 64 * 256;
    const ush* B2g = St + base + (long)tn * 64 * 256;
    int t = threadIdx.x;
    int lr = t >> 2, lq = t & 3;
    int w = t >> 6, lane = t & 63;
    int wr = w >> 1, wc = w & 1;
    int ml = lane & 15, quad = lane >> 4;
    floatx4 acc1[2][2] = {};
    floatx4 acc2[2][2] = {};
#pragma unroll
    for (int h = 0; h < 2; h++) {
        __syncthreads();
#pragma unroll
        for (int rr = 0; rr < 4; rr++) {
            int col = (lq + 4 * rr) * 8;
            *(uint4*)&As[lr * LD + col]  = *(const uint4*)(Ag + lr * 256 + h * 128 + col);
            *(uint4*)&B1s[lr * LD + col] = *(const uint4*)(B1g + lr * 256 + h * 128 + col);
            if (!FINAL) *(uint4*)&B2s[lr * LD + col] = *(const uint4*)(B2g + lr * 256 + h * 128 + col);
        }
        __syncthreads();
#pragma unroll
        for (int kq = 0; kq < 4; kq++) {
            int ko = kq * 32 + quad * 8;
            short8 a0 = *(const short8*)&As[(wr * 32 + ml) * LD + ko];
            short8 a1 = *(const short8*)&As[(wr * 32 + 16 + ml) * LD + ko];
            short8 b10 = *(const short8*)&B1s[(wc * 32 + ml) * LD + ko];
            short8 b11 = *(const short8*)&B1s[(wc * 32 + 16 + ml) * LD + ko];
            acc1[0][0] = __builtin_amdgcn_mfma_f32_16x16x32_bf16(a0, b10, acc1[0][0], 0, 0, 0);
            acc1[0][1] = __builtin_amdgcn_mfma_f32_16x16x32_bf16(a0, b11, acc1[0][1], 0, 0, 0);
            acc1[1][0] = __builtin_amdgcn_mfma_f32_16x16x32_bf16(a1, b10, acc1[1][0], 0, 0, 0);
            acc1[1][1] = __builtin_amdgcn_mfma_f32_16x16x32_bf16(a1, b11, acc1[1][1], 0, 0, 0);
            if (!FINAL) {
                short8 b20 = *(const short8*)&B2s[(wc * 32 + ml) * LD + ko];
                short8 b21 = *(const short8*)&B2s[(wc * 32 + 16 + ml) * LD + ko];
                acc2[0][0] = __builtin_amdgcn_mfma_f32_16x16x32_bf16(a0, b20, acc2[0][0], 0, 0, 0);
                acc2[0][1] = __builtin_amdgcn_mfma_f32_16x16x32_bf16(a0, b21, acc2[0][1], 0, 0, 0);
                acc2[1][0] = __builtin_amdgcn_mfma_f32_16x16x32_bf16(a1, b20, acc2[1][0], 0, 0, 0);
                acc2[1][1] = __builtin_amdgcn_mfma_f32_16x16x32_bf16(a1, b21, acc2[1][1], 0, 0, 0);
            }
        }
    }
    int rowb = tm * 64 + wr * 32, colb = tn * 64 + wc * 32;
#pragma unroll
    for (int i = 0; i < 2; i++) {
#pragma unroll
        for (int j = 0; j < 2; j++) {
            int col = colb + j * 16 + ml;
            int r0 = rowb + i * 16 + quad * 4;
            ushort4v et = *(const ushort4v*)&Et[base + (long)col * 256 + r0];
            ushort4v st = *(const ushort4v*)&St[base + (long)col * 256 + r0];
            ushort4v pv;
#pragma unroll
            for (int r = 0; r < 4; r++) {
                float e = b2f(et[r]), s = b2f(st[r]);
                float p = 0.25f * (((r0 + r == col) ? 13.0f : 0.0f) - 15.0f * e + 7.0f * s - acc1[i][j][r]);
                pv[r] = f2b(p);
            }
            *(ushort4v*)&Pt[base + (long)col * 256 + r0] = pv;
            if (!FINAL) {
                ush h[4];
#pragma unroll
                for (int r = 0; r < 4; r++) {
                    float e = b2f(et[r]), s = b2f(st[r]);
                    float en = 0.25f * (13.0f * e - 15.0f * s + 7.0f * acc1[i][j][r] - acc2[i][j][r]);
                    h[r] = f2b(en);
                }
#pragma unroll
                for (int r = 0; r < 4; r++) Eo[base + (long)(r0 + r) * 256 + col] = h[r];
                ushort4v ht = { h[0], h[1], h[2], h[3] };
                *(ushort4v*)&Eot[base + (long)col * 256 + r0] = ht;
            }
        }
    }
}

// ---------------- nsW: Wt (hi/lo) = (V4 @ RV)^T, N=64 ----------------
__global__ __launch_bounds__(256) void nsW(const ush* __restrict__ V4, const ush* __restrict__ RVt,
                                           ush* __restrict__ WtH, ush* __restrict__ WtL) {
    const int LD = 136;
    __shared__ __align__(16) ush As[64 * LD];
    __shared__ __align__(16) ush Bs[64 * LD];
    int g = blockIdx.z, tm = blockIdx.y;
    long base = (long)g * 65536;
    const ush* Ag = V4 + base + (long)tm * 64 * 256;
    const ush* Bg = RVt + (long)g * 16384;
    int t = threadIdx.x;
    int lr = t >> 2, lq = t & 3;
    int w = t >> 6, lane = t & 63;
    int wr = w >> 1, wc = w & 1;
    int ml = lane & 15, quad = lane >> 4;
    floatx4 acc[2][2] = {};
#pragma unroll
    for (int h = 0; h < 2; h++) {
        __syncthreads();
#pragma unroll
        for (int rr = 0; rr < 4; rr++) {
            int col = (lq + 4 * rr) * 8;
            *(uint4*)&As[lr * LD + col] = *(const uint4*)(Ag + lr * 256 + h * 128 + col);
            *(uint4*)&Bs[lr * LD + col] = *(const uint4*)(Bg + lr * 256 + h * 128 + col);
        }
        __syncthreads();
#pragma unroll
        for (int kq = 0; kq < 4; kq++) {
            int ko = kq * 32 + quad * 8;
            short8 a0 = *(const short8*)&As[(wr * 32 + ml) * LD + ko];
            short8 a1 = *(const short8*)&As[(wr * 32 + 16 + ml) * LD + ko];
            short8 b0 = *(const short8*)&Bs[(wc * 32 + ml) * LD + ko];
            short8 b1 = *(const short8*)&Bs[(wc * 32 + 16 + ml) * LD + ko];
            acc[0][0] = __builtin_amdgcn_mfma_f32_16x16x32_bf16(a0, b0, acc[0][0], 0, 0, 0);
            acc[0][1] = __builtin_amdgcn_mfma_f32_16x16x32_bf16(a0, b1, acc[0][1], 0, 0, 0);
            acc[1][0] = __builtin_amdgcn_mfma_f32_16x16x32_bf16(a1, b0, acc[1][0], 0, 0, 0);
            acc[1][1] = __builtin_amdgcn_mfma_f32_16x16x32_bf16(a1, b1, acc[1][1], 0, 0, 0);
        }
    }
    int rowb = tm * 64 + wr * 32, colb = wc * 32;
#pragma unroll
    for (int i = 0; i < 2; i++) {
#pragma unroll
        for (int j = 0; j < 2; j++) {
            int col = colb + j * 16 + ml;
            int r0 = rowb + i * 16 + quad * 4;
            ushort4v hv, lv;
#pragma unroll
            for (int r = 0; r < 4; r++) {
                float v = acc[i][j][r];
                ush h = f2b(v);
                hv[r] = h;
                lv[r] = f2b(v - b2f(h));
            }
            *(ushort4v*)&WtH[(long)g * 16384 + (long)col * 256 + r0] = hv;
            *(ushort4v*)&WtL[(long)g * 16384 + (long)col * 256 + r0] = lv;
        }
    }
}

extern "C" void kernel_launch(void* const* d_in, const int* in_sizes, int n_in,
                              void* d_out, int out_size, void* d_ws, size_t ws_size,
                              hipStream_t stream) {
    (void)in_sizes; (void)n_in; (void)out_size; (void)ws_size;
    const float* Q = (const float*)d_in[0];
    const float* K = (const float*)d_in[1];
    const float* V = (const float*)d_in[2];

    float* ws    = (float*)d_ws;
    float* sumQ  = ws;
    float* sumK  = sumQ + 65536;
    float* k2    = sumK + 65536;
    float* nr    = k2 + 65536;
    float* u     = nr + 262144;
    float* Mb    = u + 1048576;
    float* Kmax2 = Mb + 4096;
    float* scale = Kmax2 + 16;
    float* colsum= scale + 16 + 32;
    float* Lp    = colsum + 4096;
    float* RVp   = Lp + 65536;
    int* idxQ    = (int*)(RVp + 4194304);
    int* idxK    = idxQ + 4096;
    ush* ncH     = (ush*)(idxK + 4096);
    ush* ncL     = ncH + 262144;
    ush* WtH     = ncL + 262144;
    ush* WtL     = WtH + 262144;
    ush* RVt     = WtL + 262144;
    ush* u_bf    = RVt + 262144;
    ush* Vacc_a  = u_bf + 1048576;
    ush* Vacc_b  = Vacc_a + 1048576;
    ush* E_a     = Vacc_b + 1048576;
    ush* Et_a    = E_a + 1048576;
    ush* E_b     = Et_a + 1048576;
    ush* Et_b    = E_b + 1048576;
    ush* Sbuf    = Et_b + 1048576;
    ush* St      = Sbuf + 1048576;
    ush* Ptb     = St + 1048576;

    dim3 blk(256);

    hipLaunchKernelGGL(rowsum_kernel, dim3(G * NSEQ / 16), blk, 0, stream, Q, K, sumQ, sumK, k2);
    hipLaunchKernelGGL(topk_select, dim3(G, 2), blk, 0, stream, sumQ, sumK, idxQ, idxK, k2, Kmax2, colsum);
    hipLaunchKernelGGL(gather_kernel, dim3(G * MSEL / 4), blk, 0, stream, Q, K, idxQ, idxK, Kmax2, nr, ncH, ncL, Mb);

    hipLaunchKernelGGL(flash_rv, dim3(NSL, 4, G), blk, 0, stream, nr, K, V, Mb, Lp, RVp);

    // u = softmax(nr @ nc^T) + colsum
    hipLaunchKernelGGL((fused_cx<1>), dim3(4, G), blk, 0, stream, nr, ncH, ncL,
                       (const ush*)0, (const ush*)0, u, colsum, 1.0f);

    // merged: rv_merge (z=0) + ns_prep (z=1)
    hipLaunchKernelGGL(mergeprep_kernel, dim3(16, G, 2), blk, 0, stream,
                       Lp, RVp, RVt, u, colsum, u_bf, Vacc_a, scale);

    // E0 = sc * u@u^T  (rm + t)
    hipLaunchKernelGGL(nsAC, dim3(4, 4, G), blk, 0, stream,
                       u_bf, u_bf, (const ush*)0, (const ush*)0, E_a, Et_a, (ush*)0, scale, 0);
    // S0 = E0@E0  (rm + t)
    hipLaunchKernelGGL(nsAC, dim3(4, 4, G), blk, 0, stream,
                       E_a, Et_a, (const ush*)0, (const ush*)0, Sbuf, St, (ush*)0, (const float*)0, 0);

    ush* E = E_a;  ush* Et = Et_a;
    ush* En = E_b; ush* Ent = Et_b;
    ush* Vc = Vacc_a; ush* Vn = Vacc_b;
    for (int i = 0; i < 3; i++) {
        // E' and P from S, E
        hipLaunchKernelGGL((nsB<false>), dim3(4, 4, G), blk, 0, stream, Sbuf, Et, St, En, Ent, Ptb);
        // batched: S' = E'@E' ; V' = V@P
        hipLaunchKernelGGL(nsAC, dim3(4, 4, 2 * G), blk, 0, stream,
                           En, Ent, Vc, Ptb, Sbuf, St, Vn, (const float*)0, 0);
        ush* tp;
        tp = E; E = En; En = tp;
        tp = Et; Et = Ent; Ent = tp;
        tp = Vc; Vc = Vn; Vn = tp;
    }
    // P3 only
    hipLaunchKernelGGL((nsB<true>), dim3(4, 4, G), blk, 0, stream, Sbuf, Et, St, (ush*)0, (ush*)0, Ptb);
    // V4 = V3@P3
    hipLaunchKernelGGL(nsAC, dim3(4, 4, G), blk, 0, stream,
                       (const ush*)0, (const ush*)0, Vc, Ptb, (ush*)0, (ush*)0, Vn, (const float*)0, 1);
    // Wt (hi/lo) = (V4 @ RV)^T
    hipLaunchKernelGGL(nsW, dim3(1, 4, G), blk, 0, stream, Vn, RVt, WtH, WtL);

    // X = softmax(Qs @ nc^T) @ Wt^T -> d_out
    hipLaunchKernelGGL((fused_cx<0>), dim3(64, G), blk, 0, stream, Q, ncH, ncL, WtH, WtL,
                       (float*)d_out, (float*)0, 0.125f);
}